// Round 1
// baseline (709.988 us; speedup 1.0000x reference)
//
#include <hip/hip_runtime.h>
#include <math.h>

typedef float f32x4 __attribute__((ext_vector_type(4)));
typedef short s16x8 __attribute__((ext_vector_type(8)));
typedef __bf16 bf16x8 __attribute__((ext_vector_type(8)));

static __device__ __forceinline__ short f2bf(float f) {
    union { float f; unsigned u; } v; v.f = f;
    unsigned r = (v.u + 0x7FFFu + ((v.u >> 16) & 1u)) >> 16;
    return (short)r;
}

static __device__ __forceinline__ f32x4 mfma16(bf16x8 a, bf16x8 b, f32x4 c) {
    return __builtin_amdgcn_mfma_f32_16x16x32_bf16(a, b, c, 0, 0, 0);
}

// ---------------------------------------------------------------------------
// GEMM: C[m,n] = sum_k A[m,k] * W[n,k] + bias[n]
// MODE 0: A = hidden_states fp32 [16400,1024], W = w_qkv fp32 [3072,1024]
//         epilogue -> q/k/v bf16 buffers laid out [b,head,s,d], q scaled 1/8
// MODE 1: A = ctx bf16 [16400,1024], W = w_dense fp32 [1024,1024]
//         epilogue -> fp32 out [16400,1024]
// Tile 128x128, BK=32, 256 threads = 4 waves (2x2, each wave 64x64 = 4x4 frags)
// ---------------------------------------------------------------------------
template<int MODE>
__global__ __launch_bounds__(256)
void gemm_kernel(const void* __restrict__ Av, const float* __restrict__ W,
                 const float* __restrict__ bias,
                 short* __restrict__ q_out, short* __restrict__ k_out,
                 short* __restrict__ v_out, float* __restrict__ f_out)
{
    constexpr int M = 16400;   // 16 * 1025
    constexpr int K = 1024;

    __shared__ short As[128][40];   // +8 pad: conflict-free b128 reads
    __shared__ short Bs[128][40];

    const int tid  = threadIdx.x;
    const int lane = tid & 63;
    const int wv   = tid >> 6;
    const int wr   = wv >> 1, wc = wv & 1;
    const int fr   = lane & 15, fq = lane >> 4;
    const int m0   = blockIdx.y * 128;
    const int n0   = blockIdx.x * 128;

    const int srow  = tid >> 1;     // 0..127 (tile row this thread stages)
    const int shalf = tid & 1;      // which 16-wide half of BK
    int am = m0 + srow; if (am > M - 1) am = M - 1;   // clamp (stores predicated)
    const int bn = n0 + srow;                          // N is multiple of 128

    f32x4 acc[4][4];
    #pragma unroll
    for (int i = 0; i < 4; ++i)
        #pragma unroll
        for (int j = 0; j < 4; ++j)
            acc[i][j] = f32x4{0.f, 0.f, 0.f, 0.f};

    const float* Af = (const float*)Av;
    const short* Ab = (const short*)Av;

    for (int kt = 0; kt < K / 32; ++kt) {
        const int k0 = kt * 32 + shalf * 16;
        // ---- stage A tile ----
        if constexpr (MODE == 0) {
            const float* src = Af + (size_t)am * K + k0;
            f32x4 v0 = *(const f32x4*)(src + 0);
            f32x4 v1 = *(const f32x4*)(src + 4);
            f32x4 v2 = *(const f32x4*)(src + 8);
            f32x4 v3 = *(const f32x4*)(src + 12);
            s16x8 t0, t1;
            #pragma unroll
            for (int c = 0; c < 4; ++c) {
                t0[c]     = f2bf(v0[c]);
                t0[c + 4] = f2bf(v1[c]);
                t1[c]     = f2bf(v2[c]);
                t1[c + 4] = f2bf(v3[c]);
            }
            *(s16x8*)&As[srow][shalf * 16]     = t0;
            *(s16x8*)&As[srow][shalf * 16 + 8] = t1;
        } else {
            const short* src = Ab + (size_t)am * K + k0;
            *(s16x8*)&As[srow][shalf * 16]     = *(const s16x8*)(src);
            *(s16x8*)&As[srow][shalf * 16 + 8] = *(const s16x8*)(src + 8);
        }
        // ---- stage B tile (W rows are K-contiguous: B^T layout) ----
        {
            const float* src = W + (size_t)bn * K + k0;
            f32x4 v0 = *(const f32x4*)(src + 0);
            f32x4 v1 = *(const f32x4*)(src + 4);
            f32x4 v2 = *(const f32x4*)(src + 8);
            f32x4 v3 = *(const f32x4*)(src + 12);
            s16x8 t0, t1;
            #pragma unroll
            for (int c = 0; c < 4; ++c) {
                t0[c]     = f2bf(v0[c]);
                t0[c + 4] = f2bf(v1[c]);
                t1[c]     = f2bf(v2[c]);
                t1[c + 4] = f2bf(v3[c]);
            }
            *(s16x8*)&Bs[srow][shalf * 16]     = t0;
            *(s16x8*)&Bs[srow][shalf * 16 + 8] = t1;
        }
        __syncthreads();

        bf16x8 a[4], b[4];
        #pragma unroll
        for (int i = 0; i < 4; ++i) {
            a[i] = __builtin_bit_cast(bf16x8, *(const s16x8*)&As[wr*64 + i*16 + fr][fq*8]);
            b[i] = __builtin_bit_cast(bf16x8, *(const s16x8*)&Bs[wc*64 + i*16 + fr][fq*8]);
        }
        #pragma unroll
        for (int i = 0; i < 4; ++i)
            #pragma unroll
            for (int j = 0; j < 4; ++j)
                acc[i][j] = mfma16(a[i], b[j], acc[i][j]);
        __syncthreads();
    }

    // ---- epilogue ----
    #pragma unroll
    for (int mi = 0; mi < 4; ++mi) {
        #pragma unroll
        for (int ni = 0; ni < 4; ++ni) {
            const int col = n0 + wc*64 + ni*16 + fr;       // C col = lane&15
            const float bv = bias[col];
            if constexpr (MODE == 0) {
                const int head = col / 192;        // qkv interleave: [nh, 3, hd]
                const int t    = (col / 64) % 3;
                const int d    = col % 64;
                short* dst = (t == 0) ? q_out : (t == 1 ? k_out : v_out);
                const float scale = (t == 0) ? 0.125f : 1.0f;  // fold hd^-0.5 into q
                #pragma unroll
                for (int j = 0; j < 4; ++j) {
                    const int m = m0 + wr*64 + mi*16 + fq*4 + j;   // C row
                    if (m < M) {
                        const int bb = m / 1025;
                        const int ss = m - bb * 1025;
                        dst[(((size_t)(bb*16 + head)) * 1025 + ss) * 64 + d] =
                            f2bf((acc[mi][ni][j] + bv) * scale);
                    }
                }
            } else {
                #pragma unroll
                for (int j = 0; j < 4; ++j) {
                    const int m = m0 + wr*64 + mi*16 + fq*4 + j;
                    if (m < M) f_out[(size_t)m * 1024 + col] = acc[mi][ni][j] + bv;
                }
            }
        }
    }
}

// ---------------------------------------------------------------------------
// Flash attention: one block = (b,h) x 64 q-rows (4 waves x 16 rows).
// Loop over 17 KV tiles of 64. Q held in regs. K tile + V^T tile in LDS.
// Online softmax in C-fragment layout (row=q=(lane>>4)*4+j, col=kv=lane&15).
// P round-trips through LDS to become an A-operand for PV.
// ---------------------------------------------------------------------------
__global__ __launch_bounds__(256)
void attn_kernel(const short* __restrict__ qb, const short* __restrict__ kb,
                 const short* __restrict__ vb, short* __restrict__ ctxb)
{
    constexpr int S = 1025;
    const int tid  = threadIdx.x;
    const int lane = tid & 63;
    const int w    = tid >> 6;
    const int fr   = lane & 15, fq = lane >> 4;
    const int bh   = blockIdx.y;             // 0..255
    const int q0   = blockIdx.x * 64;
    const int bb   = bh >> 4, hh = bh & 15;

    const short* qp = qb + (size_t)bh * S * 64;
    const short* kp = kb + (size_t)bh * S * 64;
    const short* vp = vb + (size_t)bh * S * 64;

    __shared__ short Ks[64][72];      // [kv][d], +8 pad
    __shared__ short Vt[64][72];      // [d][kv] (transposed), +8 pad
    __shared__ short Ps[4][16][72];   // per-wave P [q][kv]

    // Q fragments in registers (A-operand: row = lane&15, k = (lane>>4)*8+j)
    int qrow = q0 + w * 16 + fr; if (qrow > S - 1) qrow = S - 1;
    const bf16x8 qa0 = __builtin_bit_cast(bf16x8, *(const s16x8*)(qp + (size_t)qrow*64 + fq*8));
    const bf16x8 qa1 = __builtin_bit_cast(bf16x8, *(const s16x8*)(qp + (size_t)qrow*64 + 32 + fq*8));

    f32x4 ctx[4];
    #pragma unroll
    for (int di = 0; di < 4; ++di) ctx[di] = f32x4{0.f,0.f,0.f,0.f};
    float mrow[4] = {-1e30f, -1e30f, -1e30f, -1e30f};
    float lrow[4] = {0.f, 0.f, 0.f, 0.f};

    const int sr = tid >> 2;   // 0..63: kv row staged by this thread
    const int sq = tid & 3;    // 16-wide d quarter

    for (int kt = 0; kt < 17; ++kt) {
        const int kv0 = kt * 64;
        // ---- stage K tile and transposed V tile ----
        {
            int krow = kv0 + sr; if (krow > S - 1) krow = S - 1;
            const short* ksrc = kp + (size_t)krow * 64 + sq * 16;
            *(s16x8*)&Ks[sr][sq * 16]     = *(const s16x8*)(ksrc);
            *(s16x8*)&Ks[sr][sq * 16 + 8] = *(const s16x8*)(ksrc + 8);
            const short* vsrc = vp + (size_t)krow * 64 + sq * 16;
            s16x8 v0 = *(const s16x8*)(vsrc);
            s16x8 v1 = *(const s16x8*)(vsrc + 8);
            #pragma unroll
            for (int i = 0; i < 8; ++i) {
                Vt[sq * 16 + i][sr]     = v0[i];
                Vt[sq * 16 + 8 + i][sr] = v1[i];
            }
        }
        __syncthreads();

        // ---- scores: S16x64 = Q @ K^T (B-operand = K natural layout) ----
        f32x4 sc[4];
        #pragma unroll
        for (int ni = 0; ni < 4; ++ni) {
            bf16x8 kf0 = __builtin_bit_cast(bf16x8, *(const s16x8*)&Ks[ni*16 + fr][fq*8]);
            bf16x8 kf1 = __builtin_bit_cast(bf16x8, *(const s16x8*)&Ks[ni*16 + fr][32 + fq*8]);
            f32x4 z = f32x4{0.f,0.f,0.f,0.f};
            z = mfma16(qa0, kf0, z);
            sc[ni] = mfma16(qa1, kf1, z);
        }
        // mask out-of-range kv
        #pragma unroll
        for (int ni = 0; ni < 4; ++ni) {
            if (kv0 + ni*16 + fr >= S) {
                sc[ni][0] = -1e30f; sc[ni][1] = -1e30f;
                sc[ni][2] = -1e30f; sc[ni][3] = -1e30f;
            }
        }

        // ---- online softmax (per q-row; row j lives in lanes sharing fq) ----
        float alpha[4];
        float p[4][4];
        #pragma unroll
        for (int j = 0; j < 4; ++j) {
            float r = fmaxf(fmaxf(sc[0][j], sc[1][j]), fmaxf(sc[2][j], sc[3][j]));
            r = fmaxf(r, __shfl_xor(r, 1, 64));
            r = fmaxf(r, __shfl_xor(r, 2, 64));
            r = fmaxf(r, __shfl_xor(r, 4, 64));
            r = fmaxf(r, __shfl_xor(r, 8, 64));
            const float mnew = fmaxf(mrow[j], r);
            alpha[j] = expf(mrow[j] - mnew);
            #pragma unroll
            for (int ni = 0; ni < 4; ++ni) p[ni][j] = expf(sc[ni][j] - mnew);
            float s = (p[0][j] + p[1][j]) + (p[2][j] + p[3][j]);
            s += __shfl_xor(s, 1, 64);
            s += __shfl_xor(s, 2, 64);
            s += __shfl_xor(s, 4, 64);
            s += __shfl_xor(s, 8, 64);
            lrow[j] = lrow[j] * alpha[j] + s;
            mrow[j] = mnew;
        }
        #pragma unroll
        for (int di = 0; di < 4; ++di) {
            #pragma unroll
            for (int j = 0; j < 4; ++j) ctx[di][j] *= alpha[j];
        }

        // ---- P -> LDS (bf16) ----
        #pragma unroll
        for (int ni = 0; ni < 4; ++ni)
            #pragma unroll
            for (int j = 0; j < 4; ++j)
                Ps[w][fq*4 + j][ni*16 + fr] = f2bf(p[ni][j]);
        __syncthreads();

        // ---- PV: ctx16x64 += P @ V  (A = P from LDS, B = V via Vt rows) ----
        #pragma unroll
        for (int ks = 0; ks < 2; ++ks) {
            bf16x8 pa = __builtin_bit_cast(bf16x8, *(const s16x8*)&Ps[w][fr][ks*32 + fq*8]);
            #pragma unroll
            for (int di = 0; di < 4; ++di) {
                bf16x8 vf = __builtin_bit_cast(bf16x8, *(const s16x8*)&Vt[di*16 + fr][ks*32 + fq*8]);
                ctx[di] = mfma16(pa, vf, ctx[di]);
            }
        }
        __syncthreads();
    }

    // ---- finalize: ctx /= l, store bf16 to [b, s, h*64+d] ----
    #pragma unroll
    for (int di = 0; di < 4; ++di) {
        #pragma unroll
        for (int j = 0; j < 4; ++j) {
            const int qg = q0 + w*16 + fq*4 + j;
            if (qg < S) {
                const float val = ctx[di][j] / lrow[j];
                ctxb[((size_t)bb * 1025 + qg) * 1024 + hh * 64 + di * 16 + fr] = f2bf(val);
            }
        }
    }
}

// ---------------------------------------------------------------------------
extern "C" void kernel_launch(void* const* d_in, const int* in_sizes, int n_in,
                              void* d_out, int out_size, void* d_ws, size_t ws_size,
                              hipStream_t stream)
{
    const float* hs      = (const float*)d_in[0];
    const float* w_qkv   = (const float*)d_in[1];
    const float* b_qkv   = (const float*)d_in[2];
    const float* w_dense = (const float*)d_in[3];
    const float* b_dense = (const float*)d_in[4];

    const size_t per = (size_t)16 * 16 * 1025 * 64;   // B*nh*S*hd elements
    short* qb   = (short*)d_ws;
    short* kb   = qb + per;
    short* vb   = kb + per;
    short* ctxb = vb + per;   // B*S*H = same element count

    dim3 blk(256);
    // QKV projection: M=16400, N=3072 -> grid (24, 129)
    gemm_kernel<0><<<dim3(24, 129), blk, 0, stream>>>(
        hs, w_qkv, b_qkv, qb, kb, vb, nullptr);
    // attention: 17 q-tiles x 256 (b,h) pairs
    attn_kernel<<<dim3(17, 256), blk, 0, stream>>>(qb, kb, vb, ctxb);
    // output projection: M=16400, N=1024 -> grid (8, 129)
    gemm_kernel<1><<<dim3(8, 129), blk, 0, stream>>>(
        ctxb, w_dense, b_dense, nullptr, nullptr, nullptr, (float*)d_out);
}

// Round 2
// 553.425 us; speedup vs baseline: 1.2829x; 1.2829x over previous
//
#include <hip/hip_runtime.h>
#include <math.h>

typedef float f32x4 __attribute__((ext_vector_type(4)));
typedef __bf16 bf16x8 __attribute__((ext_vector_type(8)));
typedef unsigned int u32;

#define AS1 __attribute__((address_space(1)))
#define AS3 __attribute__((address_space(3)))

static __device__ __forceinline__ void gload16(const void* g, void* l) {
    __builtin_amdgcn_global_load_lds((const AS1 u32*)g, (AS3 u32*)l, 16, 0, 0);
}
static __device__ __forceinline__ f32x4 mfma16(bf16x8 a, bf16x8 b, f32x4 c) {
    return __builtin_amdgcn_mfma_f32_16x16x32_bf16(a, b, c, 0, 0, 0);
}
static __device__ __forceinline__ float exp2fast(float x) {
    return __builtin_amdgcn_exp2f(x);
}

// ---------------------------------------------------------------------------
// fp32 -> bf16 bulk convert (n = grid*256*8 exactly)
// ---------------------------------------------------------------------------
__global__ __launch_bounds__(256)
void convert_kernel(const float* __restrict__ in, __bf16* __restrict__ out)
{
    const size_t i = ((size_t)blockIdx.x * 256 + threadIdx.x) * 8;
    f32x4 a = *(const f32x4*)(in + i);
    f32x4 b = *(const f32x4*)(in + i + 4);
    bf16x8 o;
    #pragma unroll
    for (int j = 0; j < 4; ++j) { o[j] = (__bf16)a[j]; o[j + 4] = (__bf16)b[j]; }
    *(bf16x8*)(out + i) = o;
}

// ---------------------------------------------------------------------------
// bf16 GEMM, m97 structure: 128x128 tile, BK=64, global_load_lds(16B),
// XOR-swizzled granules (slot = r*8 + (c ^ (r&7)), inverse applied to the
// GLOBAL source per rule 21; read applies the same XOR).
// C[m,n] = sum_k A[m,k]*W[n,k] + bias[n]
// MODE 0: -> q (scaled 0.125*log2e) / k / v bf16, layout [b,h,s,d]
// MODE 1: -> fp32 out
// ---------------------------------------------------------------------------
template<int MODE>
__global__ __launch_bounds__(256)
void gemm_kernel(const __bf16* __restrict__ A, const __bf16* __restrict__ Bw,
                 const float* __restrict__ bias,
                 __bf16* __restrict__ q_out, __bf16* __restrict__ k_out,
                 __bf16* __restrict__ v_out, float* __restrict__ f_out)
{
    constexpr int M = 16400;   // 16 * 1025
    constexpr int K = 1024;

    __shared__ __align__(16) __bf16 As[128 * 64];
    __shared__ __align__(16) __bf16 Bs[128 * 64];

    const int tid  = threadIdx.x;
    const int lane = tid & 63;
    const int wv   = tid >> 6;
    const int wr   = wv >> 1, wc = wv & 1;
    const int fr   = lane & 15, fq = lane >> 4;
    const int m0   = blockIdx.y * 128;
    const int n0   = blockIdx.x * 128;

    // staging precompute: thread stages granule-slots s = qd*256+tid
    const __bf16* aptr[4];
    const __bf16* bptr[4];
    int loff[4];
    #pragma unroll
    for (int qd = 0; qd < 4; ++qd) {
        const int s  = qd * 256 + tid;
        const int r  = s >> 3;
        const int c  = (s & 7) ^ (r & 7);     // logical k-granule held by slot s
        loff[qd] = s * 8;
        int ar = m0 + r; if (ar > M - 1) ar = M - 1;
        aptr[qd] = A  + (size_t)ar * K + c * 8;
        bptr[qd] = Bw + (size_t)(n0 + r) * K + c * 8;
    }

    f32x4 acc[4][4];
    #pragma unroll
    for (int i = 0; i < 4; ++i)
        #pragma unroll
        for (int j = 0; j < 4; ++j)
            acc[i][j] = f32x4{0.f, 0.f, 0.f, 0.f};

    for (int kt = 0; kt < K / 64; ++kt) {
        const int kof = kt * 64;
        #pragma unroll
        for (int qd = 0; qd < 4; ++qd) {
            gload16(aptr[qd] + kof, &As[loff[qd]]);
            gload16(bptr[qd] + kof, &Bs[loff[qd]]);
        }
        __syncthreads();

        #pragma unroll
        for (int ks = 0; ks < 2; ++ks) {
            bf16x8 a[4], b[4];
            #pragma unroll
            for (int i = 0; i < 4; ++i) {
                const int ra = wr * 64 + i * 16 + fr;
                const int rb = wc * 64 + i * 16 + fr;
                const int cg = ((ks * 4 + fq) ^ (fr & 7)) * 8;
                a[i] = *(const bf16x8*)&As[ra * 64 + cg];
                b[i] = *(const bf16x8*)&Bs[rb * 64 + cg];
            }
            #pragma unroll
            for (int i = 0; i < 4; ++i)
                #pragma unroll
                for (int j = 0; j < 4; ++j)
                    acc[i][j] = mfma16(a[i], b[j], acc[i][j]);
        }
        __syncthreads();
    }

    // ---- epilogue ----
    #pragma unroll
    for (int ni = 0; ni < 4; ++ni) {
        const int col = n0 + wc * 64 + ni * 16 + fr;   // C col = lane&15
        const float bv = bias[col];
        if constexpr (MODE == 0) {
            const int head = col / 192;       // qkv interleave [nh, 3, hd]
            const int t    = (col >> 6) % 3;
            const int d    = col & 63;
            __bf16* dst = (t == 0) ? q_out : (t == 1 ? k_out : v_out);
            // fold hd^-0.5 AND log2(e) into q (softmax uses exp2)
            const float scale = (t == 0) ? 0.18033688011112042f : 1.0f;
            #pragma unroll
            for (int mi = 0; mi < 4; ++mi) {
                #pragma unroll
                for (int j = 0; j < 4; ++j) {
                    const int m = m0 + wr * 64 + mi * 16 + fq * 4 + j;
                    if (m < M) {
                        const int bb = m / 1025;
                        const int ss = m - bb * 1025;
                        dst[(((size_t)(bb * 16 + head)) * 1025 + ss) * 64 + d] =
                            (__bf16)((acc[mi][ni][j] + bv) * scale);
                    }
                }
            }
        } else {
            #pragma unroll
            for (int mi = 0; mi < 4; ++mi) {
                #pragma unroll
                for (int j = 0; j < 4; ++j) {
                    const int m = m0 + wr * 64 + mi * 16 + fq * 4 + j;
                    if (m < M) f_out[(size_t)m * 1024 + col] = acc[mi][ni][j] + bv;
                }
            }
        }
    }
}

// ---------------------------------------------------------------------------
// V transpose: [bh][s][64] -> [bh][64][S2=1088] (cols >= 1025 are garbage,
// masked by p=0 in attention)
// ---------------------------------------------------------------------------
__global__ __launch_bounds__(256)
void transpose_v(const __bf16* __restrict__ vb, __bf16* __restrict__ vt)
{
    constexpr int S = 1025, S2 = 1088;
    const int bh = blockIdx.y;
    const int s0 = blockIdx.x * 64;
    const int sr = threadIdx.x >> 2, sq = threadIdx.x & 3;
    int srow = s0 + sr; if (srow > S - 1) srow = S - 1;
    const __bf16* src = vb + ((size_t)bh * S + srow) * 64 + sq * 16;
    bf16x8 v0 = *(const bf16x8*)src;
    bf16x8 v1 = *(const bf16x8*)(src + 8);
    __bf16* dst = vt + (size_t)bh * 64 * S2 + s0 + sr;   // column s0+sr (unclamped)
    #pragma unroll
    for (int i = 0; i < 8; ++i) {
        dst[(size_t)(sq * 16 + i) * S2]     = v0[i];
        dst[(size_t)(sq * 16 + 8 + i) * S2] = v1[i];
    }
}

// ---------------------------------------------------------------------------
// Flash attention. Q pre-scaled by 0.125*log2e; softmax in exp2 domain.
// K staged natural [kv][d]; V^T staged from pre-transposed global (linear
// b128 LDS writes -> no transpose conflicts).
// ---------------------------------------------------------------------------
__global__ __launch_bounds__(256)
void attn_kernel(const __bf16* __restrict__ qb, const __bf16* __restrict__ kb,
                 const __bf16* __restrict__ vtb, __bf16* __restrict__ ctxb)
{
    constexpr int S = 1025, S2 = 1088;
    const int tid  = threadIdx.x;
    const int lane = tid & 63;
    const int w    = tid >> 6;
    const int fr   = lane & 15, fq = lane >> 4;
    const int bh   = blockIdx.y;
    const int q0   = blockIdx.x * 64;
    const int bb   = bh >> 4, hh = bh & 15;

    const __bf16* qp = qb  + (size_t)bh * S * 64;
    const __bf16* kp = kb  + (size_t)bh * S * 64;
    const __bf16* vp = vtb + (size_t)bh * 64 * S2;

    __shared__ __align__(16) __bf16 Ks[64][72];      // [kv][d]
    __shared__ __align__(16) __bf16 Vt[64][72];      // [d][kv]
    __shared__ __align__(16) __bf16 Ps[4][16][72];   // per-wave P [q][kv]

    int qrow = q0 + w * 16 + fr; if (qrow > S - 1) qrow = S - 1;
    const bf16x8 qa0 = *(const bf16x8*)(qp + (size_t)qrow * 64 + fq * 8);
    const bf16x8 qa1 = *(const bf16x8*)(qp + (size_t)qrow * 64 + 32 + fq * 8);

    f32x4 ctx[4];
    #pragma unroll
    for (int di = 0; di < 4; ++di) ctx[di] = f32x4{0.f, 0.f, 0.f, 0.f};
    float mrow[4] = {-1e30f, -1e30f, -1e30f, -1e30f};
    float lrow[4] = {0.f, 0.f, 0.f, 0.f};

    const int sr = tid >> 2;   // staging row
    const int sq = tid & 3;    // staging 16-col quarter

    for (int kt = 0; kt < 17; ++kt) {
        const int kv0 = kt * 64;
        // ---- stage K (natural) and V^T (pre-transposed global) ----
        {
            int krow = kv0 + sr; if (krow > S - 1) krow = S - 1;
            const __bf16* ksrc = kp + (size_t)krow * 64 + sq * 16;
            *(bf16x8*)&Ks[sr][sq * 16]     = *(const bf16x8*)(ksrc);
            *(bf16x8*)&Ks[sr][sq * 16 + 8] = *(const bf16x8*)(ksrc + 8);
            const __bf16* vsrc = vp + (size_t)sr * S2 + kv0 + sq * 16;
            *(bf16x8*)&Vt[sr][sq * 16]     = *(const bf16x8*)(vsrc);
            *(bf16x8*)&Vt[sr][sq * 16 + 8] = *(const bf16x8*)(vsrc + 8);
        }
        __syncthreads();

        // ---- QK^T ----
        f32x4 sc[4];
        #pragma unroll
        for (int ni = 0; ni < 4; ++ni) {
            bf16x8 kf0 = *(const bf16x8*)&Ks[ni * 16 + fr][fq * 8];
            bf16x8 kf1 = *(const bf16x8*)&Ks[ni * 16 + fr][32 + fq * 8];
            f32x4 z = f32x4{0.f, 0.f, 0.f, 0.f};
            z = mfma16(qa0, kf0, z);
            sc[ni] = mfma16(qa1, kf1, z);
        }
        if (kv0 + 64 > S) {   // masked tail tile only
            #pragma unroll
            for (int ni = 0; ni < 4; ++ni) {
                if (kv0 + ni * 16 + fr >= S) {
                    sc[ni][0] = -1e30f; sc[ni][1] = -1e30f;
                    sc[ni][2] = -1e30f; sc[ni][3] = -1e30f;
                }
            }
        }

        // ---- online softmax (exp2 domain) ----
        float alpha[4];
        float p[4][4];
        #pragma unroll
        for (int j = 0; j < 4; ++j) {
            float r = fmaxf(fmaxf(sc[0][j], sc[1][j]), fmaxf(sc[2][j], sc[3][j]));
            r = fmaxf(r, __shfl_xor(r, 1, 64));
            r = fmaxf(r, __shfl_xor(r, 2, 64));
            r = fmaxf(r, __shfl_xor(r, 4, 64));
            r = fmaxf(r, __shfl_xor(r, 8, 64));
            const float mnew = fmaxf(mrow[j], r);
            alpha[j] = exp2fast(mrow[j] - mnew);
            float s = 0.f;
            #pragma unroll
            for (int ni = 0; ni < 4; ++ni) {
                p[ni][j] = exp2fast(sc[ni][j] - mnew);
                s += p[ni][j];
            }
            s += __shfl_xor(s, 1, 64);
            s += __shfl_xor(s, 2, 64);
            s += __shfl_xor(s, 4, 64);
            s += __shfl_xor(s, 8, 64);
            lrow[j] = lrow[j] * alpha[j] + s;
            mrow[j] = mnew;
        }
        #pragma unroll
        for (int di = 0; di < 4; ++di) {
            #pragma unroll
            for (int j = 0; j < 4; ++j) ctx[di][j] *= alpha[j];
        }

        // ---- P -> LDS (bf16) ----
        #pragma unroll
        for (int ni = 0; ni < 4; ++ni)
            #pragma unroll
            for (int j = 0; j < 4; ++j)
                Ps[w][fq * 4 + j][ni * 16 + fr] = (__bf16)p[ni][j];
        __syncthreads();

        // ---- PV ----
        #pragma unroll
        for (int ks = 0; ks < 2; ++ks) {
            bf16x8 pa = *(const bf16x8*)&Ps[w][fr][ks * 32 + fq * 8];
            #pragma unroll
            for (int di = 0; di < 4; ++di) {
                bf16x8 vf = *(const bf16x8*)&Vt[di * 16 + fr][ks * 32 + fq * 8];
                ctx[di] = mfma16(pa, vf, ctx[di]);
            }
        }
        __syncthreads();
    }

    // ---- finalize ----
    #pragma unroll
    for (int di = 0; di < 4; ++di) {
        #pragma unroll
        for (int j = 0; j < 4; ++j) {
            const int qg = q0 + w * 16 + fq * 4 + j;
            if (qg < S) {
                ctxb[((size_t)bb * 1025 + qg) * 1024 + hh * 64 + di * 16 + fr] =
                    (__bf16)(ctx[di][j] / lrow[j]);
            }
        }
    }
}

// ---------------------------------------------------------------------------
extern "C" void kernel_launch(void* const* d_in, const int* in_sizes, int n_in,
                              void* d_out, int out_size, void* d_ws, size_t ws_size,
                              hipStream_t stream)
{
    const float* hs      = (const float*)d_in[0];
    const float* w_qkv   = (const float*)d_in[1];
    const float* b_qkv   = (const float*)d_in[2];
    const float* w_dense = (const float*)d_in[3];
    const float* b_dense = (const float*)d_in[4];

    const size_t nHS = (size_t)16 * 1025 * 1024;      // 16,793,600
    const size_t nWQ = (size_t)3072 * 1024;           //  3,145,728
    const size_t nWD = (size_t)1024 * 1024;           //  1,048,576
    const size_t nVT = (size_t)256 * 64 * 1088;       // 17,825,792

    __bf16* hsb     = (__bf16*)d_ws;
    __bf16* wqkvb   = hsb + nHS;
    __bf16* wdenseb = wqkvb + nWQ;
    __bf16* qb      = wdenseb + nWD;
    __bf16* kb      = qb + nHS;
    __bf16* vb      = kb + nHS;
    __bf16* ctxb    = vb + nHS;
    __bf16* vtb     = ctxb + nHS;
    (void)nVT;

    dim3 blk(256);
    convert_kernel<<<dim3((unsigned)(nHS / 2048)), blk, 0, stream>>>(hs, hsb);
    convert_kernel<<<dim3((unsigned)(nWQ / 2048)), blk, 0, stream>>>(w_qkv, wqkvb);
    convert_kernel<<<dim3((unsigned)(nWD / 2048)), blk, 0, stream>>>(w_dense, wdenseb);

    gemm_kernel<0><<<dim3(24, 129), blk, 0, stream>>>(
        hsb, wqkvb, b_qkv, qb, kb, vb, nullptr);

    transpose_v<<<dim3(17, 256), blk, 0, stream>>>(vb, vtb);

    attn_kernel<<<dim3(17, 256), blk, 0, stream>>>(qb, kb, vtb, ctxb);

    gemm_kernel<1><<<dim3(8, 129), blk, 0, stream>>>(
        ctxb, wdenseb, b_dense, nullptr, nullptr, nullptr, (float*)d_out);
}

// Round 3
// 454.000 us; speedup vs baseline: 1.5639x; 1.2190x over previous
//
#include <hip/hip_runtime.h>
#include <math.h>

typedef float f32x4 __attribute__((ext_vector_type(4)));
typedef __bf16 bf16x8 __attribute__((ext_vector_type(8)));
typedef unsigned int u32;
typedef u32 u32x4 __attribute__((ext_vector_type(4)));

#define AS1 __attribute__((address_space(1)))
#define AS3 __attribute__((address_space(3)))

static __device__ __forceinline__ void gload16(const void* g, void* l) {
    __builtin_amdgcn_global_load_lds((const AS1 u32*)g, (AS3 u32*)l, 16, 0, 0);
}
static __device__ __forceinline__ f32x4 mfma16(bf16x8 a, bf16x8 b, f32x4 c) {
    return __builtin_amdgcn_mfma_f32_16x16x32_bf16(a, b, c, 0, 0, 0);
}
static __device__ __forceinline__ float exp2fast(float x) {
    return __builtin_amdgcn_exp2f(x);
}

// ---------------------------------------------------------------------------
// fp32 -> bf16 bulk convert (n = grid*256*8 exactly)
// ---------------------------------------------------------------------------
__global__ __launch_bounds__(256)
void convert_kernel(const float* __restrict__ in, __bf16* __restrict__ out)
{
    const size_t i = ((size_t)blockIdx.x * 256 + threadIdx.x) * 8;
    f32x4 a = *(const f32x4*)(in + i);
    f32x4 b = *(const f32x4*)(in + i + 4);
    bf16x8 o;
    #pragma unroll
    for (int j = 0; j < 4; ++j) { o[j] = (__bf16)a[j]; o[j + 4] = (__bf16)b[j]; }
    *(bf16x8*)(out + i) = o;
}

// ---------------------------------------------------------------------------
// bf16 GEMM, m97 structure: 128x128 tile, BK=64, global_load_lds(16B),
// XOR-swizzled granules. C[m,n] = sum_k A[m,k]*W[n,k] + bias[n]
// MODE 0: -> q (scaled 0.125*log2e) / k / v bf16, layout [b,h,s,d]
// MODE 1: -> fp32 out
// ---------------------------------------------------------------------------
template<int MODE>
__global__ __launch_bounds__(256)
void gemm_kernel(const __bf16* __restrict__ A, const __bf16* __restrict__ Bw,
                 const float* __restrict__ bias,
                 __bf16* __restrict__ q_out, __bf16* __restrict__ k_out,
                 __bf16* __restrict__ v_out, float* __restrict__ f_out)
{
    constexpr int M = 16400;   // 16 * 1025
    constexpr int K = 1024;

    __shared__ __align__(16) __bf16 As[128 * 64];
    __shared__ __align__(16) __bf16 Bs[128 * 64];

    const int tid  = threadIdx.x;
    const int lane = tid & 63;
    const int wv   = tid >> 6;
    const int wr   = wv >> 1, wc = wv & 1;
    const int fr   = lane & 15, fq = lane >> 4;
    const int m0   = blockIdx.y * 128;
    const int n0   = blockIdx.x * 128;

    const __bf16* aptr[4];
    const __bf16* bptr[4];
    int loff[4];
    #pragma unroll
    for (int qd = 0; qd < 4; ++qd) {
        const int s  = qd * 256 + tid;
        const int r  = s >> 3;
        const int c  = (s & 7) ^ (r & 7);
        loff[qd] = s * 8;
        int ar = m0 + r; if (ar > M - 1) ar = M - 1;
        aptr[qd] = A  + (size_t)ar * K + c * 8;
        bptr[qd] = Bw + (size_t)(n0 + r) * K + c * 8;
    }

    f32x4 acc[4][4];
    #pragma unroll
    for (int i = 0; i < 4; ++i)
        #pragma unroll
        for (int j = 0; j < 4; ++j)
            acc[i][j] = f32x4{0.f, 0.f, 0.f, 0.f};

    for (int kt = 0; kt < K / 64; ++kt) {
        const int kof = kt * 64;
        #pragma unroll
        for (int qd = 0; qd < 4; ++qd) {
            gload16(aptr[qd] + kof, &As[loff[qd]]);
            gload16(bptr[qd] + kof, &Bs[loff[qd]]);
        }
        __syncthreads();

        #pragma unroll
        for (int ks = 0; ks < 2; ++ks) {
            bf16x8 a[4], b[4];
            #pragma unroll
            for (int i = 0; i < 4; ++i) {
                const int ra = wr * 64 + i * 16 + fr;
                const int rb = wc * 64 + i * 16 + fr;
                const int cg = ((ks * 4 + fq) ^ (fr & 7)) * 8;
                a[i] = *(const bf16x8*)&As[ra * 64 + cg];
                b[i] = *(const bf16x8*)&Bs[rb * 64 + cg];
            }
            #pragma unroll
            for (int i = 0; i < 4; ++i)
                #pragma unroll
                for (int j = 0; j < 4; ++j)
                    acc[i][j] = mfma16(a[i], b[j], acc[i][j]);
        }
        __syncthreads();
    }

    #pragma unroll
    for (int ni = 0; ni < 4; ++ni) {
        const int col = n0 + wc * 64 + ni * 16 + fr;
        const float bv = bias[col];
        if constexpr (MODE == 0) {
            const int head = col / 192;
            const int t    = (col >> 6) % 3;
            const int d    = col & 63;
            __bf16* dst = (t == 0) ? q_out : (t == 1 ? k_out : v_out);
            const float scale = (t == 0) ? 0.18033688011112042f : 1.0f;
            #pragma unroll
            for (int mi = 0; mi < 4; ++mi) {
                #pragma unroll
                for (int j = 0; j < 4; ++j) {
                    const int m = m0 + wr * 64 + mi * 16 + fq * 4 + j;
                    if (m < M) {
                        const int bb = m / 1025;
                        const int ss = m - bb * 1025;
                        dst[(((size_t)(bb * 16 + head)) * 1025 + ss) * 64 + d] =
                            (__bf16)((acc[mi][ni][j] + bv) * scale);
                    }
                }
            }
        } else {
            #pragma unroll
            for (int mi = 0; mi < 4; ++mi) {
                #pragma unroll
                for (int j = 0; j < 4; ++j) {
                    const int m = m0 + wr * 64 + mi * 16 + fq * 4 + j;
                    if (m < M) f_out[(size_t)m * 1024 + col] = acc[mi][ni][j] + bv;
                }
            }
        }
    }
}

// ---------------------------------------------------------------------------
// V transpose: [bh][s][64] -> [bh][64][S2=1088]
// ---------------------------------------------------------------------------
__global__ __launch_bounds__(256)
void transpose_v(const __bf16* __restrict__ vb, __bf16* __restrict__ vt)
{
    constexpr int S = 1025, S2 = 1088;
    const int bh = blockIdx.y;
    const int s0 = blockIdx.x * 64;
    const int sr = threadIdx.x >> 2, sq = threadIdx.x & 3;
    int srow = s0 + sr; if (srow > S - 1) srow = S - 1;
    const __bf16* src = vb + ((size_t)bh * S + srow) * 64 + sq * 16;
    bf16x8 v0 = *(const bf16x8*)src;
    bf16x8 v1 = *(const bf16x8*)(src + 8);
    __bf16* dst = vt + (size_t)bh * 64 * S2 + s0 + sr;
    #pragma unroll
    for (int i = 0; i < 8; ++i) {
        dst[(size_t)(sq * 16 + i) * S2]     = v0[i];
        dst[(size_t)(sq * 16 + 8 + i) * S2] = v1[i];
    }
}

// ---------------------------------------------------------------------------
// Flash attention, SWAPPED QK^T: sc = mfma(K, Q) -> lane owns one q-row
// (q = lane&15), 16 kv values. Softmax per-thread + 2 shfl. T13 defer-max.
// P repacked to PV A-operand via wave-private LDS row (2-way, no barrier).
// K/V staged by global_load_lds with XOR-granule swizzle.
// ---------------------------------------------------------------------------
__global__ __launch_bounds__(256)
void attn_kernel(const __bf16* __restrict__ qb, const __bf16* __restrict__ kb,
                 const __bf16* __restrict__ vtb, __bf16* __restrict__ ctxb)
{
    constexpr int S = 1025, S2 = 1088;
    const int tid  = threadIdx.x;
    const int lane = tid & 63;
    const int w    = tid >> 6;
    const int fr   = lane & 15, fq = lane >> 4;
    const int bh   = blockIdx.y;
    const int q0   = blockIdx.x * 64;
    const int bb   = bh >> 4, hh = bh & 15;

    const __bf16* qp = qb  + (size_t)bh * S * 64;
    const __bf16* kp = kb  + (size_t)bh * S * 64;
    const __bf16* vp = vtb + (size_t)bh * 64 * S2;

    __shared__ __align__(16) __bf16 Ks[64 * 64];   // swizzled granules [kv][d]
    __shared__ __align__(16) __bf16 Vs[64 * 64];   // swizzled granules [d][kv]
    __shared__ u32 Ps[4][16 * 33];                 // wave-private P rows

    // staging slots (2 per thread per tensor)
    const int s0i = tid, s1i = tid + 256;
    const int r0 = s0i >> 3, g0 = (s0i & 7) ^ (r0 & 7);
    const int r1 = s1i >> 3, g1 = (s1i & 7) ^ (r1 & 7);
    const __bf16* vsrc0 = vp + (size_t)r0 * S2 + g0 * 8;
    const __bf16* vsrc1 = vp + (size_t)r1 * S2 + g1 * 8;

    // Q fragments (same regs serve as B-operand of swapped QK^T)
    int qrow = q0 + w * 16 + fr; if (qrow > S - 1) qrow = S - 1;
    const bf16x8 qa0 = *(const bf16x8*)(qp + (size_t)qrow * 64 + fq * 8);
    const bf16x8 qa1 = *(const bf16x8*)(qp + (size_t)qrow * 64 + 32 + fq * 8);

    f32x4 ctx[4];
    #pragma unroll
    for (int di = 0; di < 4; ++di) ctx[di] = f32x4{0.f, 0.f, 0.f, 0.f};
    float mrow = -1e30f;     // per-thread: q = fr
    float lrow = 0.f;

    u32* psrow_w = &Ps[w][fr * 33];

    for (int kt = 0; kt < 17; ++kt) {
        const int kv0 = kt * 64;
        // ---- stage K and V^T via global_load_lds ----
        {
            int kr0 = kv0 + r0; if (kr0 > S - 1) kr0 = S - 1;
            int kr1 = kv0 + r1; if (kr1 > S - 1) kr1 = S - 1;
            gload16(kp + (size_t)kr0 * 64 + g0 * 8, &Ks[s0i * 8]);
            gload16(kp + (size_t)kr1 * 64 + g1 * 8, &Ks[s1i * 8]);
            gload16(vsrc0 + kv0, &Vs[s0i * 8]);
            gload16(vsrc1 + kv0, &Vs[s1i * 8]);
        }
        __syncthreads();

        // ---- QK^T (swapped): D[kv][q], lane: col=fr=q, row=fq*4+j=kv%16 ----
        f32x4 sc[4];
        #pragma unroll
        for (int ni = 0; ni < 4; ++ni) {
            const int row = ni * 16 + fr;
            bf16x8 kf0 = *(const bf16x8*)&Ks[row * 64 + ((fq    ) ^ (row & 7)) * 8];
            bf16x8 kf1 = *(const bf16x8*)&Ks[row * 64 + ((fq + 4) ^ (row & 7)) * 8];
            f32x4 z = f32x4{0.f, 0.f, 0.f, 0.f};
            z = mfma16(kf0, qa0, z);
            sc[ni] = mfma16(kf1, qa1, z);
        }
        if (kv0 + 64 > S) {
            #pragma unroll
            for (int ni = 0; ni < 4; ++ni)
                #pragma unroll
                for (int j = 0; j < 4; ++j)
                    if (kv0 + ni * 16 + fq * 4 + j >= S) sc[ni][j] = -1e30f;
        }

        // ---- softmax: per-thread row max over 16 + cross-fq reduce ----
        float mt = sc[0][0];
        #pragma unroll
        for (int ni = 0; ni < 4; ++ni)
            #pragma unroll
            for (int j = 0; j < 4; ++j) mt = fmaxf(mt, sc[ni][j]);
        mt = fmaxf(mt, __shfl_xor(mt, 16, 64));
        mt = fmaxf(mt, __shfl_xor(mt, 32, 64));

        // T13 defer-max: rescale only when some row grew past threshold
        if (__any(mt > mrow + 8.0f)) {
            const float mnew = fmaxf(mrow, mt);
            const float alpha = exp2fast(mrow - mnew);
            mrow = mnew;
            lrow *= alpha;
            float a[4];
            #pragma unroll
            for (int j = 0; j < 4; ++j) a[j] = __shfl(alpha, fq * 4 + j, 64);
            #pragma unroll
            for (int di = 0; di < 4; ++di) {
                ctx[di][0] *= a[0]; ctx[di][1] *= a[1];
                ctx[di][2] *= a[2]; ctx[di][3] *= a[3];
            }
        }

        float p[4][4];
        float s = 0.f;
        #pragma unroll
        for (int ni = 0; ni < 4; ++ni)
            #pragma unroll
            for (int j = 0; j < 4; ++j) {
                p[ni][j] = exp2fast(sc[ni][j] - mrow);
                s += p[ni][j];
            }
        s += __shfl_xor(s, 16, 64);
        s += __shfl_xor(s, 32, 64);
        lrow += s;

        // ---- pack P pairs and exchange via wave-private LDS row ----
        #pragma unroll
        for (int ni = 0; ni < 4; ++ni) {
            #pragma unroll
            for (int h = 0; h < 2; ++h) {
                unsigned short lo = __builtin_bit_cast(unsigned short, (__bf16)p[ni][2 * h]);
                unsigned short hi = __builtin_bit_cast(unsigned short, (__bf16)p[ni][2 * h + 1]);
                psrow_w[fq * 8 + ni * 2 + h] = (u32)lo | ((u32)hi << 16);
            }
        }
        u32x4 pav[2];
        #pragma unroll
        for (int ks = 0; ks < 2; ++ks)
            #pragma unroll
            for (int t = 0; t < 4; ++t) {
                const int slot = (2 * (fq & 1) + (t >> 1)) * 8
                               + (2 * ks + (fq >> 1)) * 2 + (t & 1);
                pav[ks][t] = psrow_w[slot];
            }

        // ---- PV: ctx[di] += P @ V ----
        #pragma unroll
        for (int ks = 0; ks < 2; ++ks) {
            const bf16x8 pa = __builtin_bit_cast(bf16x8, pav[ks]);
            #pragma unroll
            for (int di = 0; di < 4; ++di) {
                const int row = di * 16 + fr;
                bf16x8 vf = *(const bf16x8*)&Vs[row * 64 + ((ks * 4 + fq) ^ (row & 7)) * 8];
                ctx[di] = mfma16(pa, vf, ctx[di]);
            }
        }
        __syncthreads();
    }

    // ---- finalize: broadcast l per ctx row, divide, store ----
    float linv[4];
    #pragma unroll
    for (int j = 0; j < 4; ++j) linv[j] = 1.0f / __shfl(lrow, fq * 4 + j, 64);
    #pragma unroll
    for (int di = 0; di < 4; ++di) {
        #pragma unroll
        for (int j = 0; j < 4; ++j) {
            const int qg = q0 + w * 16 + fq * 4 + j;
            if (qg < S) {
                ctxb[((size_t)bb * 1025 + qg) * 1024 + hh * 64 + di * 16 + fr] =
                    (__bf16)(ctx[di][j] * linv[j]);
            }
        }
    }
}

// ---------------------------------------------------------------------------
extern "C" void kernel_launch(void* const* d_in, const int* in_sizes, int n_in,
                              void* d_out, int out_size, void* d_ws, size_t ws_size,
                              hipStream_t stream)
{
    const float* hs      = (const float*)d_in[0];
    const float* w_qkv   = (const float*)d_in[1];
    const float* b_qkv   = (const float*)d_in[2];
    const float* w_dense = (const float*)d_in[3];
    const float* b_dense = (const float*)d_in[4];

    const size_t nHS = (size_t)16 * 1025 * 1024;
    const size_t nWQ = (size_t)3072 * 1024;
    const size_t nWD = (size_t)1024 * 1024;

    __bf16* hsb     = (__bf16*)d_ws;
    __bf16* wqkvb   = hsb + nHS;
    __bf16* wdenseb = wqkvb + nWQ;
    __bf16* qb      = wdenseb + nWD;
    __bf16* kb      = qb + nHS;
    __bf16* vb      = kb + nHS;
    __bf16* ctxb    = vb + nHS;
    __bf16* vtb     = ctxb + nHS;

    dim3 blk(256);
    convert_kernel<<<dim3((unsigned)(nHS / 2048)), blk, 0, stream>>>(hs, hsb);
    convert_kernel<<<dim3((unsigned)(nWQ / 2048)), blk, 0, stream>>>(w_qkv, wqkvb);
    convert_kernel<<<dim3((unsigned)(nWD / 2048)), blk, 0, stream>>>(w_dense, wdenseb);

    gemm_kernel<0><<<dim3(24, 129), blk, 0, stream>>>(
        hsb, wqkvb, b_qkv, qb, kb, vb, nullptr);

    transpose_v<<<dim3(17, 256), blk, 0, stream>>>(vb, vtb);

    attn_kernel<<<dim3(17, 256), blk, 0, stream>>>(qb, kb, vtb, ctxb);

    gemm_kernel<1><<<dim3(8, 129), blk, 0, stream>>>(
        ctxb, wdenseb, b_dense, nullptr, nullptr, nullptr, (float*)d_out);
}